// Round 3
// baseline (157.671 us; speedup 1.0000x reference)
//
#include <hip/hip_runtime.h>
#include <stdint.h>

#define N_LOC 216320        // 5 * 208 * 208
#define PLANE 43264         // 208 * 208
#define GRIDW 208
#define NCAP 2048           // candidate cap (expected ~1060)
#define TOPK 1024

typedef unsigned long long u64;
typedef uint32_t u32;

// ---- workspace layout (bytes) ----
// meta region [0, 41152) is zeroed by ONE hipMemsetAsync per call
#define OFF_BOX       0u          // float4[1024] = 16384
#define OFF_HIST      16384u      // u32[4096]    = 16384
#define OFF_CONF      32768u      // f32[1024]    = 4096
#define OFF_CLS       36864u      // f32[1024]    = 4096
#define OFF_NZ        40960u      // u64[16]      = 128
#define OFF_CTR       41088u      // u32[16]      = 64   [0]=M [1]=thr [2]=doneA [3]=doneD
#define META_BYTES    41152u
#define OFF_CAND      41152u      // u64[2048]    = 16384
#define OFF_SUP       57536u      // u64[1024*16] = 131072
#define OFF_KEYS      188608u     // u32[216320]  = 865280  (end ~1.03 MB)

__device__ __forceinline__ u32 aload32(const u32* p) {
    return __hip_atomic_load(p, __ATOMIC_RELAXED, __HIP_MEMORY_SCOPE_AGENT);
}
__device__ __forceinline__ u64 aload64(const u64* p) {
    return __hip_atomic_load(p, __ATOMIC_RELAXED, __HIP_MEMORY_SCOPE_AGENT);
}

// conf scores + histogram of mantissa bits [22:11]; last block finds the
// threshold bin containing rank TOPK (counting from the top).
__global__ void __launch_bounds__(256) k_scores(const float* __restrict__ x,
                                                u32* keys, u32* hist, u32* ctr) {
    int i = blockIdx.x * 256 + threadIdx.x;   // grid exactly covers N_LOC
    int a = i / PLANE;
    int hw = i - a * PLANE;
    float v = x[(a * 85 + 4) * PLANE + hw];
    float cf = 1.0f / (1.0f + expf(-v));
    u32 key = (cf > 0.5f) ? __float_as_uint(cf) : 0u;
    keys[i] = key;
    if (key) {
        u32 bin = (key >= 0x3F800000u) ? 4095u : ((key >> 11) & 0xFFFu);
        atomicAdd(&hist[bin], 1u);
    }
    // last-block-done handshake
    __shared__ int isLast;
    __syncthreads();                       // drain this block's atomics
    if (threadIdx.x == 0) {
        __threadfence();                   // release
        u32 old = atomicAdd(&ctr[2], 1u);
        isLast = (old == gridDim.x - 1u);
    }
    __syncthreads();
    if (!isLast) return;
    __threadfence();                       // acquire
    // findbin (256 threads)
    __shared__ u32 lhist[4096];
    __shared__ u32 csum[256];
    int t = threadIdx.x;
    u32 s = 0;
    for (int b = 0; b < 16; b++) {
        u32 h = aload32(&hist[t * 16 + b]);
        lhist[t * 16 + b] = h;
        s += h;
    }
    csum[t] = s;
    __syncthreads();
    if (t == 0) {
        u32 acc = 0;
        int selB = 0;
        int c = 255;
        for (; c >= 0; c--) {
            if (acc + csum[c] >= (u32)TOPK) break;
            acc += csum[c];
        }
        if (c >= 0) {
            int b = c * 16 + 15;
            for (; b >= c * 16; b--) {
                acc += lhist[b];
                if (acc >= (u32)TOPK) break;
            }
            if (b < c * 16) b = c * 16;   // defensive
            selB = b;
        }
        ctr[1] = 0x3F000000u | ((u32)selB << 11);  // visible at next dispatch
    }
}

// compact candidates with key >= threshold into cand[] as (key<<32)|~idx
__global__ void __launch_bounds__(256) k_compact(const u32* __restrict__ keys,
                                                 u32* ctr, u64* cand) {
    int i = blockIdx.x * 256 + threadIdx.x;
    u32 k = keys[i];
    u32 thr = ctr[1];                      // thr >= 0x3F000000 > 0, so k>=thr => k!=0
    if (k >= thr) {
        u32 pos = atomicAdd(&ctr[0], 1u);
        if (pos < (u32)NCAP)
            cand[pos] = ((u64)k << 32) | (u64)(~(u32)i);
    }
}

// one WAVE per candidate: exact rank (= jax.lax.top_k position: desc conf,
// ties -> lower index; keys unique) then in-place wave-parallel decode.
__global__ void __launch_bounds__(64) k_rankdec(const float* __restrict__ x,
                                                const float* __restrict__ anchors,
                                                const u32* __restrict__ ctr,
                                                const u64* __restrict__ cand,
                                                float4* box, float* conf, float* clsf) {
    u32 M = ctr[0];
    if (M > (u32)NCAP) M = NCAP;
    u32 b = blockIdx.x;
    if (b >= M) return;
    u64 key = cand[b];
    int lane = threadIdx.x;
    u32 cnt = 0;
    for (u32 j = (u32)lane; j < M; j += 64) cnt += (cand[j] > key) ? 1u : 0u;
    for (int off = 32; off; off >>= 1) cnt += __shfl_xor(cnt, off);
    if (cnt >= (u32)TOPK) return;
    u32 rank = cnt;
    u32 i = ~((u32)key);
    u32 a = i / PLANE;
    u32 hw = i - a * PLANE;
    u32 h = hw / GRIDW;
    u32 w = hw - h * GRIDW;
    const float* base = x + (size_t)(a * 85u) * PLANE + hw;
    // classes: lane l -> class l; lanes 0..15 also class 64+l
    float v0 = base[(5 + lane) * PLANE];
    int   c0 = lane;
    if (lane < 16) {
        float v1 = base[(5 + 64 + lane) * PLANE];
        if (v1 > v0) { v0 = v1; c0 = 64 + lane; }   // tie keeps lower idx
    }
    float pv = (lane < 4) ? base[lane * PLANE] : 0.f;
    // butterfly argmax, tie -> lower class index (jnp.argmax first-occurrence)
    for (int off = 32; off; off >>= 1) {
        float ov = __shfl_xor(v0, off);
        int   oc = __shfl_xor(c0, off);
        if (ov > v0 || (ov == v0 && oc < c0)) { v0 = ov; c0 = oc; }
    }
    float p0 = __shfl(pv, 0);
    float p1 = __shfl(pv, 1);
    float p2 = __shfl(pv, 2);
    float p3 = __shfl(pv, 3);
    if (lane == 0) {
        float bx = (1.0f / (1.0f + expf(-p0)) + (float)w) * 32.0f;
        float by = (1.0f / (1.0f + expf(-p1)) + (float)h) * 32.0f;
        float bw = (expf(p2) * anchors[a * 2 + 0]) * 32.0f;
        float bh = (expf(p3) * anchors[a * 2 + 1]) * 32.0f;
        box[rank] = make_float4(bx, by, bw, bh);
        conf[rank] = __uint_as_float((u32)(key >> 32));
        clsf[rank] = (float)c0;
    }
}

// suppression bitmatrix (256 blocks x 4 rows, boxes staged in LDS), fused
// with the greedy NMS scan + output write in the last-finishing block.
__global__ void __launch_bounds__(256) k_sup_nms(const float4* __restrict__ box,
                                                 const float* __restrict__ clsf,
                                                 const float* __restrict__ conf,
                                                 u64* sup, u64* nz, u32* ctr,
                                                 float* __restrict__ out) {
    __shared__ float4 sbox[1024];
    __shared__ float  scls[1024];
    __shared__ u64 wany[4];
    int t = threadIdx.x;
    for (int c = 0; c < 4; c++) {
        int j = c * 256 + t;
        sbox[j] = box[j];
        scls[j] = clsf[j];
    }
    __syncthreads();
    u32 rowflags = 0;                      // meaningful in thread 0 only
    for (int r = 0; r < 4; r++) {
        int i = blockIdx.x * 4 + r;
        float4 bi = sbox[i];
        float ci = scls[i];
        // faithful to reference: (c - s)/2 parenthesization
        float x1min = (bi.x - bi.z) * 0.5f, x1max = (bi.x + bi.z) * 0.5f;
        float y1min = (bi.y - bi.w) * 0.5f, y1max = (bi.y + bi.w) * 0.5f;
        float a1 = fabsf((x1max - x1min) * (y1max - y1min));
        u64 any = 0;
        for (int c = 0; c < 4; c++) {
            int j = c * 256 + t;
            bool sfl = false;
            if (j > i) {
                float4 bj = sbox[j];
                float x2min = (bj.x - bj.z) * 0.5f, x2max = (bj.x + bj.z) * 0.5f;
                float y2min = (bj.y - bj.w) * 0.5f, y2max = (bj.y + bj.w) * 0.5f;
                float iw = fmaxf(fminf(x1max, x2max) - fmaxf(x1min, x2min), 0.0f);
                float ih = fmaxf(fminf(y1max, y2max) - fmaxf(y1min, y2min), 0.0f);
                float inter = iw * ih;
                float a2 = fabsf((x2max - x2min) * (y2max - y2min));
                float iou = inter / (a1 + a2 - inter + 1e-6f);
                sfl = (iou >= 0.5f) && (scls[j] == ci);
            }
            u64 msk = __ballot(sfl);
            if ((t & 63) == 0) sup[i * 16 + c * 4 + (t >> 6)] = msk;
            any |= msk;
        }
        if ((t & 63) == 0) wany[t >> 6] = any;
        __syncthreads();
        if (t == 0) {
            if (wany[0] | wany[1] | wany[2] | wany[3]) rowflags |= 1u << r;
        }
        __syncthreads();
    }
    // last-block-done handshake
    __shared__ int isLast;
    if (t == 0) {
        if (rowflags)
            atomicOr(&nz[(4u * blockIdx.x) >> 6], (u64)rowflags << ((4u * blockIdx.x) & 63u));
        __threadfence();                   // release (writes back dirty L2)
        u32 old = atomicAdd(&ctr[3], 1u);
        isLast = (old == gridDim.x - 1u);
    }
    __syncthreads();
    if (!isLast) return;
    __threadfence();                       // acquire
    // candmask from conf (written in previous dispatch -> plain loads ok)
    __shared__ u64 candLDS[16];
    __shared__ u64 nzLDS[16];
    __shared__ u64 remLDS[16];
    for (int c = 0; c < 4; c++) {
        bool valid = conf[c * 256 + t] > 0.0f;
        u64 bm = __ballot(valid);
        if ((t & 63) == 0) candLDS[c * 4 + (t >> 6)] = bm;
    }
    if (t < 16) nzLDS[t] = aload64(&nz[t]);
    __syncthreads();
    if (t < 64) {
        int lane = t;
        u64 rem = 0;
        u64 cnd = (lane < 16) ? candLDS[lane] : 0ull;
        u64 nzw = (lane < 16) ? nzLDS[lane] : 0ull;
        for (int g = 0; g < 16; g++) {
            u64 myword = cnd & ~rem;
            u64 live = __shfl(myword, g);
            u64 act = live & __shfl(nzw, g);
            while (act) {
                int bb = __builtin_ctzll(act);
                int i2 = g * 64 + bb;
                u64 row = (lane < 16) ? aload64(&sup[i2 * 16 + lane]) : 0ull;
                rem |= row;
                u64 row_g = __shfl(row, g);
                act &= ~row_g;
                act &= ~(1ull << bb);
            }
        }
        if (lane < 16) remLDS[lane] = rem;
    }
    __syncthreads();
    for (int c = 0; c < 4; c++) {
        int r = c * 256 + t;
        u64 cw = candLDS[r >> 6];
        u64 rw = remLDS[r >> 6];
        bool kept = ((cw >> (r & 63)) & 1ull) && !((rw >> (r & 63)) & 1ull);
        float4 b4 = sbox[r];
        float cf = conf[r];
        float cl = scls[r];
        float* o = out + r * 6;
        if (kept) {
            o[0] = b4.x; o[1] = b4.y; o[2] = b4.z; o[3] = b4.w; o[4] = cf; o[5] = cl;
        } else {
            o[0] = 0.f; o[1] = 0.f; o[2] = 0.f; o[3] = 0.f; o[4] = 0.f; o[5] = 0.f;
        }
    }
}

extern "C" void kernel_launch(void* const* d_in, const int* in_sizes, int n_in,
                              void* d_out, int out_size, void* d_ws, size_t ws_size,
                              hipStream_t stream) {
    const float* x = (const float*)d_in[0];
    const float* anchors = (const float*)d_in[1];
    float* out = (float*)d_out;
    char* ws = (char*)d_ws;

    float4* box   = (float4*)(ws + OFF_BOX);
    u32* hist     = (u32*)(ws + OFF_HIST);
    float* conf   = (float*)(ws + OFF_CONF);
    float* clsf   = (float*)(ws + OFF_CLS);
    u64* nz       = (u64*)(ws + OFF_NZ);
    u32* ctr      = (u32*)(ws + OFF_CTR);
    u64* cand     = (u64*)(ws + OFF_CAND);
    u64* sup      = (u64*)(ws + OFF_SUP);
    u32* keys     = (u32*)(ws + OFF_KEYS);

    hipMemsetAsync(ws, 0, META_BYTES, stream);
    k_scores<<<N_LOC / 256, 256, 0, stream>>>(x, keys, hist, ctr);
    k_compact<<<N_LOC / 256, 256, 0, stream>>>(keys, ctr, cand);
    k_rankdec<<<NCAP, 64, 0, stream>>>(x, anchors, ctr, cand, box, conf, clsf);
    k_sup_nms<<<256, 256, 0, stream>>>(box, clsf, conf, sup, nz, ctr, out);
}